// Round 2
// baseline (202.745 us; speedup 1.0000x reference)
//
#include <hip/hip_runtime.h>
#include <math.h>

#define N_F   128
#define N_D   2048
#define BATCH 8
#define ALPHA 0.2f
#define NJC   8     // j-slices per firefly
#define JSL   16    // j's per slice

// ws layout (floats):
//   [0   .. 127]   sq_orig[i]
//   [128 .. 255]   sq_final[i]  (zeroed by K1, atomic-accumulated by K3)
//   [512 ..]       partial sums: [i][jc][N_D]  (128*8*2048 = 8 MB)
//   [512 + 128*8*2048 ..] pos_final rows (128 x 2048)
#define WS_SQO   0
#define WS_SQF   128
#define WS_PART  512
#define WS_POSF  (512 + N_F * NJC * N_D)

// K1: per-firefly squared norm of original positions; zero sq_final slot.
__global__ __launch_bounds__(256) void ff_k1_norms(const float* __restrict__ pos,
                                                   float* __restrict__ ws) {
    const int i   = blockIdx.x;
    const int tid = threadIdx.x;            // 256 threads
    const float* row = pos + (size_t)i * N_D;
    float4 a = *(const float4*)(row + tid * 4);
    float4 b = *(const float4*)(row + 1024 + tid * 4);
    float ss = a.x*a.x + a.y*a.y + a.z*a.z + a.w*a.w
             + b.x*b.x + b.y*b.y + b.z*b.z + b.w*b.w;
    __shared__ float red[256];
    red[tid] = ss;
    __syncthreads();
    for (int s = 128; s > 0; s >>= 1) {
        if (tid < s) red[tid] += red[tid + s];
        __syncthreads();
    }
    if (tid == 0) {
        ws[WS_SQO + i] = red[0];
        ws[WS_SQF + i] = 0.0f;   // init for K3's atomic accumulation
    }
}

// K2: block (i, jc, c) sums accepted noise rows j in [jc*16, jc*16+16)
// over dim chunk c (1024 floats), writes deterministic partial to ws.
// 2048 blocks x 256 threads -> 8 blocks/CU, full 32 waves/CU occupancy.
// Inner loop: 4 row-loads batched into independent registers (4x MLP),
// but accumulated in strict ascending-j order -> bit-identical result.
__global__ __launch_bounds__(256) void ff_k2_partial(const float* __restrict__ noise,
                                                     float* __restrict__ ws) {
    const int i    = blockIdx.x;
    const int jc   = blockIdx.y;
    const int c    = blockIdx.z;
    const int tid  = threadIdx.x;
    const int wave = tid >> 6;
    const int lane = tid & 63;

    __shared__ float s_sq[N_F];
    __shared__ unsigned char s_list[JSL];
    __shared__ int s_n;

    if (tid < N_F) s_sq[tid] = ws[WS_SQO + tid];
    __syncthreads();
    const float si = s_sq[i];
    if (wave == 0) {
        const int j = jc * JSL + lane;          // lanes 0..15 valid
        const bool cond = (lane < JSL) && (j != i) && (s_sq[j] < si);
        const unsigned long long m = __ballot(cond);
        if (cond) {
            int p = __popcll(m & ((1ULL << lane) - 1ULL));
            s_list[p] = (unsigned char)j;       // compaction preserves ascending j
        }
        if (lane == 0) s_n = __popcll(m);
    }
    __syncthreads();
    const int nacc = s_n;

    const int d0 = c * 1024 + tid * 4;
    const float* nbase = noise + (size_t)i * (N_F * N_D) + d0;

    float4 acc = make_float4(0.f, 0.f, 0.f, 0.f);
    int t = 0;
    // 4-deep load batching; adds stay in ascending-j order (single accumulator).
    for (; t + 4 <= nacc; t += 4) {
        const float* p0 = nbase + ((size_t)s_list[t]     << 11);
        const float* p1 = nbase + ((size_t)s_list[t + 1] << 11);
        const float* p2 = nbase + ((size_t)s_list[t + 2] << 11);
        const float* p3 = nbase + ((size_t)s_list[t + 3] << 11);
        const float4 v0 = *(const float4*)p0;
        const float4 v1 = *(const float4*)p1;
        const float4 v2 = *(const float4*)p2;
        const float4 v3 = *(const float4*)p3;
        acc.x += v0.x; acc.y += v0.y; acc.z += v0.z; acc.w += v0.w;
        acc.x += v1.x; acc.y += v1.y; acc.z += v1.z; acc.w += v1.w;
        acc.x += v2.x; acc.y += v2.y; acc.z += v2.z; acc.w += v2.w;
        acc.x += v3.x; acc.y += v3.y; acc.z += v3.z; acc.w += v3.w;
    }
    for (; t < nacc; ++t) {
        const float4 v = *(const float4*)(nbase + ((size_t)s_list[t] << 11));
        acc.x += v.x; acc.y += v.y; acc.z += v.z; acc.w += v.w;
    }
    *(float4*)(ws + WS_PART + ((size_t)(i * NJC + jc)) * N_D + d0) = acc;
}

// K3: fold 8 partials + positions -> pos_final + ||pos_final||^2.
// grid (128, 2): all 256 CUs active. Per-element pf math identical to before
// (bit-identical pos_final); the norm is joined by a commutative 2-way atomic
// (only consumed by argmin comparisons).
__global__ __launch_bounds__(256) void ff_k3_fold(const float* __restrict__ pos,
                                                  float* __restrict__ ws) {
    const int i   = blockIdx.x;
    const int c   = blockIdx.y;
    const int tid = threadIdx.x;            // 256 threads, 1 float4 slot each
    const int d   = c * 1024 + tid * 4;

    float4 acc = make_float4(0.f, 0.f, 0.f, 0.f);
    #pragma unroll
    for (int jc = 0; jc < NJC; ++jc) {
        const float4 v = *(const float4*)(ws + WS_PART +
                            ((size_t)(i * NJC + jc)) * N_D + d);
        acc.x += v.x; acc.y += v.y; acc.z += v.z; acc.w += v.w;
    }
    const float4 p = *(const float4*)(pos + (size_t)i * N_D + d);
    float4 pf;
    pf.x = fmaf(ALPHA, acc.x, p.x);
    pf.y = fmaf(ALPHA, acc.y, p.y);
    pf.z = fmaf(ALPHA, acc.z, p.z);
    pf.w = fmaf(ALPHA, acc.w, p.w);
    *(float4*)(ws + WS_POSF + (size_t)i * N_D + d) = pf;

    float ss = pf.x*pf.x + pf.y*pf.y + pf.z*pf.z + pf.w*pf.w;
    __shared__ float red[256];
    red[tid] = ss;
    __syncthreads();
    for (int s = 128; s > 0; s >>= 1) {
        if (tid < s) red[tid] += red[tid + s];
        __syncthreads();
    }
    if (tid == 0) atomicAdd(&ws[WS_SQF + i], red[0]);
}

// K4: argmin over sq_final (first-index tie-break) + broadcast to (BATCH, N_D).
__global__ __launch_bounds__(256) void ff_k4_out(const float* __restrict__ best_intensity,
                                                 const float* __restrict__ best_position,
                                                 const float* __restrict__ ws,
                                                 float* __restrict__ out) {
    const int tid = threadIdx.x;            // 256 threads, 16 blocks
    __shared__ float sv[N_F];
    __shared__ int   sidx[N_F];
    if (tid < N_F) { sv[tid] = ws[WS_SQF + tid]; sidx[tid] = tid; }
    __syncthreads();
    for (int s = 64; s > 0; s >>= 1) {
        if (tid < s) {
            float v2 = sv[tid + s];
            int   i2 = sidx[tid + s];
            if (v2 < sv[tid] || (v2 == sv[tid] && i2 < sidx[tid])) {
                sv[tid] = v2; sidx[tid] = i2;
            }
        }
        __syncthreads();
    }
    const int  best   = sidx[0];
    const bool better = sqrtf(sv[0]) < best_intensity[0];
    const float* src  = better ? (ws + WS_POSF + (size_t)best * N_D)
                               : best_position;
    const int t = blockIdx.x * 256 + tid;   // 0..4095 float4 slots
    const int d = (t << 2) & (N_D - 1);
    float4 v = *(const float4*)(src + d);
    *(float4*)(out + (size_t)t * 4) = v;
}

extern "C" void kernel_launch(void* const* d_in, const int* in_sizes, int n_in,
                              void* d_out, int out_size, void* d_ws, size_t ws_size,
                              hipStream_t stream) {
    const float* positions      = (const float*)d_in[1];
    const float* noise          = (const float*)d_in[2];
    const float* best_position  = (const float*)d_in[3];
    const float* best_intensity = (const float*)d_in[4];
    float* ws  = (float*)d_ws;
    float* out = (float*)d_out;

    ff_k1_norms<<<N_F, 256, 0, stream>>>(positions, ws);
    dim3 g2(N_F, NJC, 2);
    ff_k2_partial<<<g2, 256, 0, stream>>>(noise, ws);
    dim3 g3(N_F, 2);
    ff_k3_fold<<<g3, 256, 0, stream>>>(positions, ws);
    ff_k4_out<<<16, 256, 0, stream>>>(best_intensity, best_position, ws, out);
}

// Round 3
// 199.787 us; speedup vs baseline: 1.0148x; 1.0148x over previous
//
#include <hip/hip_runtime.h>
#include <math.h>

#define N_F   128
#define N_D   2048
#define BATCH 8
#define ALPHA 0.2f

// ws layout (floats):
//   [0   .. 127]   sq_orig[i]
//   [128 .. 255]   sq_final[i]  (zeroed by K1, atomic-accumulated by K23)
//   [512 + 128*8*2048 ..] pos_final rows (128 x 2048)  (offset kept from prior layout)
#define WS_SQO   0
#define WS_SQF   128
#define WS_POSF  (512 + N_F * 8 * N_D)

// K1: per-firefly squared norm of original positions; zero sq_final slot.
__global__ __launch_bounds__(256) void ff_k1_norms(const float* __restrict__ pos,
                                                   float* __restrict__ ws) {
    const int i   = blockIdx.x;
    const int tid = threadIdx.x;            // 256 threads
    const float* row = pos + (size_t)i * N_D;
    float4 a = *(const float4*)(row + tid * 4);
    float4 b = *(const float4*)(row + 1024 + tid * 4);
    float ss = a.x*a.x + a.y*a.y + a.z*a.z + a.w*a.w
             + b.x*b.x + b.y*b.y + b.z*b.z + b.w*b.w;
    __shared__ float red[256];
    red[tid] = ss;
    __syncthreads();
    for (int s = 128; s > 0; s >>= 1) {
        if (tid < s) red[tid] += red[tid + s];
        __syncthreads();
    }
    if (tid == 0) {
        ws[WS_SQO + i] = red[0];
        ws[WS_SQF + i] = 0.0f;   // init for K23's atomic accumulation
    }
}

// K23: fused accept + accumulate + fold + norm.
// Block (i, c): c selects a 1024-float half of dim space. Builds the full
// ascending accepted-j list once, then sums accepted noise rows directly in
// registers, grouped per 16-j slice (slice sums added in ascending slice
// order) -- bit-identical association to the previous K2-partials + K3-fold.
// Eliminates the 16 MB partial round-trip and one dispatch.
__global__ __launch_bounds__(256) void ff_k23(const float* __restrict__ noise,
                                              const float* __restrict__ pos,
                                              float* __restrict__ ws) {
    const int i    = blockIdx.x;
    const int c    = blockIdx.y;
    const int tid  = threadIdx.x;
    const int wave = tid >> 6;
    const int lane = tid & 63;

    __shared__ float s_sq[N_F];
    __shared__ unsigned char s_list[N_F];
    __shared__ int s_off[9];                       // prefix offsets per 16-j slice
    __shared__ unsigned long long s_m[2];

    if (tid < N_F) s_sq[tid] = ws[WS_SQO + tid];
    __syncthreads();
    const float si = s_sq[i];

    // waves 0,1 ballot acceptance for j = wave*64 + lane (wave-uniform branch)
    if (wave < 2) {
        const int j = wave * 64 + lane;
        const bool cond = (j != i) && (s_sq[j] < si);
        const unsigned long long m = __ballot(cond);
        if (lane == 0) s_m[wave] = m;
    }
    __syncthreads();

    // slice prefix offsets (8 slices of 16 j's)
    if (tid == 0) {
        int off = 0;
        #pragma unroll
        for (int jc = 0; jc < 8; ++jc) {
            s_off[jc] = off;
            const unsigned long long m = s_m[jc >> 2];
            off += __popcll((m >> ((jc & 3) * 16)) & 0xFFFFULL);
        }
        s_off[8] = off;
    }
    __syncthreads();

    // fill list in global ascending-j order
    if (wave < 2) {
        const int j = wave * 64 + lane;
        const bool cond = (j != i) && (s_sq[j] < si);
        if (cond) {
            const unsigned long long m = s_m[wave];
            const int base = s_off[wave * 4];       // accepted count below this wave
            const int p    = __popcll(m & ((1ULL << lane) - 1ULL));
            s_list[base + p] = (unsigned char)j;
        }
    }
    __syncthreads();

    const int d0 = c * 1024 + tid * 4;
    const float* nbase = noise + (size_t)i * (N_F * N_D) + d0;

    float4 acc = make_float4(0.f, 0.f, 0.f, 0.f);
    #pragma unroll 1
    for (int jc = 0; jc < 8; ++jc) {
        const int beg = s_off[jc];
        const int end = s_off[jc + 1];
        float4 s = make_float4(0.f, 0.f, 0.f, 0.f);
        int t = beg;
        // 8-deep load batching (MLP for 1-block/CU occupancy); adds stay in
        // ascending-j order with a single accumulator -> bit-identical.
        for (; t + 8 <= end; t += 8) {
            const float4 v0 = *(const float4*)(nbase + ((size_t)s_list[t]     << 11));
            const float4 v1 = *(const float4*)(nbase + ((size_t)s_list[t + 1] << 11));
            const float4 v2 = *(const float4*)(nbase + ((size_t)s_list[t + 2] << 11));
            const float4 v3 = *(const float4*)(nbase + ((size_t)s_list[t + 3] << 11));
            const float4 v4 = *(const float4*)(nbase + ((size_t)s_list[t + 4] << 11));
            const float4 v5 = *(const float4*)(nbase + ((size_t)s_list[t + 5] << 11));
            const float4 v6 = *(const float4*)(nbase + ((size_t)s_list[t + 6] << 11));
            const float4 v7 = *(const float4*)(nbase + ((size_t)s_list[t + 7] << 11));
            s.x += v0.x; s.y += v0.y; s.z += v0.z; s.w += v0.w;
            s.x += v1.x; s.y += v1.y; s.z += v1.z; s.w += v1.w;
            s.x += v2.x; s.y += v2.y; s.z += v2.z; s.w += v2.w;
            s.x += v3.x; s.y += v3.y; s.z += v3.z; s.w += v3.w;
            s.x += v4.x; s.y += v4.y; s.z += v4.z; s.w += v4.w;
            s.x += v5.x; s.y += v5.y; s.z += v5.z; s.w += v5.w;
            s.x += v6.x; s.y += v6.y; s.z += v6.z; s.w += v6.w;
            s.x += v7.x; s.y += v7.y; s.z += v7.z; s.w += v7.w;
        }
        for (; t + 4 <= end; t += 4) {
            const float4 v0 = *(const float4*)(nbase + ((size_t)s_list[t]     << 11));
            const float4 v1 = *(const float4*)(nbase + ((size_t)s_list[t + 1] << 11));
            const float4 v2 = *(const float4*)(nbase + ((size_t)s_list[t + 2] << 11));
            const float4 v3 = *(const float4*)(nbase + ((size_t)s_list[t + 3] << 11));
            s.x += v0.x; s.y += v0.y; s.z += v0.z; s.w += v0.w;
            s.x += v1.x; s.y += v1.y; s.z += v1.z; s.w += v1.w;
            s.x += v2.x; s.y += v2.y; s.z += v2.z; s.w += v2.w;
            s.x += v3.x; s.y += v3.y; s.z += v3.z; s.w += v3.w;
        }
        for (; t < end; ++t) {
            const float4 v = *(const float4*)(nbase + ((size_t)s_list[t] << 11));
            s.x += v.x; s.y += v.y; s.z += v.z; s.w += v.w;
        }
        acc.x += s.x; acc.y += s.y; acc.z += s.z; acc.w += s.w;
    }

    const float4 p = *(const float4*)(pos + (size_t)i * N_D + d0);
    float4 pf;
    pf.x = fmaf(ALPHA, acc.x, p.x);
    pf.y = fmaf(ALPHA, acc.y, p.y);
    pf.z = fmaf(ALPHA, acc.z, p.z);
    pf.w = fmaf(ALPHA, acc.w, p.w);
    *(float4*)(ws + WS_POSF + (size_t)i * N_D + d0) = pf;

    float ss = pf.x*pf.x + pf.y*pf.y + pf.z*pf.z + pf.w*pf.w;
    __shared__ float red[256];
    red[tid] = ss;
    __syncthreads();
    for (int s = 128; s > 0; s >>= 1) {
        if (tid < s) red[tid] += red[tid + s];
        __syncthreads();
    }
    if (tid == 0) atomicAdd(&ws[WS_SQF + i], red[0]);  // 2-way commutative join
}

// K4: argmin over sq_final (first-index tie-break) + broadcast to (BATCH, N_D).
__global__ __launch_bounds__(256) void ff_k4_out(const float* __restrict__ best_intensity,
                                                 const float* __restrict__ best_position,
                                                 const float* __restrict__ ws,
                                                 float* __restrict__ out) {
    const int tid = threadIdx.x;            // 256 threads, 16 blocks
    __shared__ float sv[N_F];
    __shared__ int   sidx[N_F];
    if (tid < N_F) { sv[tid] = ws[WS_SQF + tid]; sidx[tid] = tid; }
    __syncthreads();
    for (int s = 64; s > 0; s >>= 1) {
        if (tid < s) {
            float v2 = sv[tid + s];
            int   i2 = sidx[tid + s];
            if (v2 < sv[tid] || (v2 == sv[tid] && i2 < sidx[tid])) {
                sv[tid] = v2; sidx[tid] = i2;
            }
        }
        __syncthreads();
    }
    const int  best   = sidx[0];
    const bool better = sqrtf(sv[0]) < best_intensity[0];
    const float* src  = better ? (ws + WS_POSF + (size_t)best * N_D)
                               : best_position;
    const int t = blockIdx.x * 256 + tid;   // 0..4095 float4 slots
    const int d = (t << 2) & (N_D - 1);
    float4 v = *(const float4*)(src + d);
    *(float4*)(out + (size_t)t * 4) = v;
}

extern "C" void kernel_launch(void* const* d_in, const int* in_sizes, int n_in,
                              void* d_out, int out_size, void* d_ws, size_t ws_size,
                              hipStream_t stream) {
    const float* positions      = (const float*)d_in[1];
    const float* noise          = (const float*)d_in[2];
    const float* best_position  = (const float*)d_in[3];
    const float* best_intensity = (const float*)d_in[4];
    float* ws  = (float*)d_ws;
    float* out = (float*)d_out;

    ff_k1_norms<<<N_F, 256, 0, stream>>>(positions, ws);
    dim3 g23(N_F, 2);
    ff_k23<<<g23, 256, 0, stream>>>(noise, positions, ws);
    ff_k4_out<<<16, 256, 0, stream>>>(best_intensity, best_position, ws, out);
}